// Round 4
// baseline (2097.490 us; speedup 1.0000x reference)
//
#include <hip/hip_runtime.h>

// AR LSTM decoder, B=256, T=2048, IN=64, H=32, NCLS=5.
//
// R8: hide the serial-chain stall (~800 cy/step residual, R4-R7 evidence) by
// interleaving TWO independent batch rows in one consumer wave.
//   - block = 1 producer wave (gx for rows 2p, 2p+1) + 1 consumer wave
//     (both recurrences, statement-interleaved; weights shared, state split).
//   - grid = 128 blocks (B/2).
//   - consumer stores RAW logits to out[]; a ~20us postpass kernel applies
//     log-softmax in place with R7's exact max/sum/log ordering
//     (bit-identical). Ring + producer drain deleted.
//   - recurrence math per chain is R7's verbatim (chain-exact accumulation).

namespace {

typedef float f2 __attribute__((ext_vector_type(2)));
typedef unsigned int u32;
typedef const __attribute__((address_space(1))) u32* gas_ptr;
typedef __attribute__((address_space(3))) u32* las_ptr;

constexpr int Tn  = 2048;
constexpr int INn = 64;
constexpr int Hn  = 32;
constexpr int NC  = 5;
constexpr int CH  = 32;            // steps per chunk
constexpr int CHF = CH * INn;      // 2048 floats x-chunk (8 KB)
constexpr int GXF = CH * 128;      // 4096 floats gx-chunk (16 KB)
constexpr int NCHUNK = Tn / CH;    // 64

__device__ __forceinline__ float rcpf(float x) { return __builtin_amdgcn_rcpf(x); }
__device__ __forceinline__ float hadd(f2 v) { return v.x + v.y; }

__device__ __forceinline__ float rlane(float x, int l) {
    return __int_as_float(__builtin_amdgcn_readlane(__float_as_int(x), l));
}

__device__ __forceinline__ float dpp_swap1(float x) {   // quad_perm xor 1
    int t = __builtin_amdgcn_update_dpp(0, __float_as_int(x), 0xB1, 0xF, 0xF, true);
    return __int_as_float(t);
}

__device__ __forceinline__ void gl16(const float* g, float* l) {
    __builtin_amdgcn_global_load_lds((gas_ptr)g, (las_ptr)l, 16, 0, 0);
}

__device__ __forceinline__ int ld_acq(int* p) {
    return __hip_atomic_load(p, __ATOMIC_ACQUIRE, __HIP_MEMORY_SCOPE_WORKGROUP);
}
__device__ __forceinline__ void st_rel(int* p, int v) {
    __hip_atomic_store(p, v, __ATOMIC_RELEASE, __HIP_MEMORY_SCOPE_WORKGROUP);
}

__global__ __launch_bounds__(128, 1)
void ar_decode2(const float* __restrict__ x,
                const float* __restrict__ W_ih,
                const float* __restrict__ W_hh,
                const float* __restrict__ b_ih,
                const float* __restrict__ b_hh,
                const float* __restrict__ W_fc,
                const float* __restrict__ b_fc,
                const float* __restrict__ emb,
                float* __restrict__ out)
{
    const int b0   = 2 * blockIdx.x;
    const int b1   = b0 + 1;
    const int tid  = threadIdx.x;
    const int lane = tid & 63;
    const int m    = lane >> 1;
    const int par  = lane & 1;
    const bool even = (par == 0);
    const int rA = par * Hn + m;            // i-row (par0) or f-row (par1)
    const int rB = rA + 2 * Hn;             // g-row (par0) or o-row (par1)

    __shared__ __align__(16) float s_xp[2 * 2 * CHF];   // [row][buf] 32 KB
    __shared__ __align__(16) float s_gx[2 * 2 * GXF];   // [row][buf] 64 KB
    __shared__ int s_prog;   // chunks produced (both rows)
    __shared__ int s_cons;   // chunks consumed (both rows)

    if (tid == 0) { s_prog = 0; s_cons = 0; }
    __syncthreads();

    const float* __restrict__ xb0 = x + (size_t)b0 * Tn * INn;
    const float* __restrict__ xb1 = x + (size_t)b1 * Tn * INn;
    float* __restrict__ ob0 = out + (size_t)b0 * Tn * NC;
    float* __restrict__ ob1 = out + (size_t)b1 * Tn * NC;

    if (tid >= 64) {
        // ============== producer wave: gx for rows b0,b1 =====================
        f2 wA[INn / 2], wB[INn / 2];     // 128 VGPR — volatile-pinned loads
        {
            const volatile f2* pA = (const volatile f2*)(W_ih + (size_t)rA * 2 * INn);
            const volatile f2* pB = (const volatile f2*)(W_ih + (size_t)rB * 2 * INn);
            #pragma unroll
            for (int i = 0; i < INn / 2; ++i) { wA[i] = pA[i]; wB[i] = pB[i]; }
        }
        const float biasA = b_ih[rA] + b_hh[rA];
        const float biasB = b_ih[rB] + b_hh[rB];

        // prologue: chunks 0,1 for both rows (16 loads per chunk, oldest-first)
        #pragma unroll
        for (int r = 0; r < 8; ++r) gl16(xb0 + r * 256 + lane * 4, s_xp + 0 * 2 * CHF + r * 256);
        #pragma unroll
        for (int r = 0; r < 8; ++r) gl16(xb1 + r * 256 + lane * 4, s_xp + 1 * 2 * CHF + r * 256);
        #pragma unroll
        for (int r = 0; r < 8; ++r) gl16(xb0 + CHF + r * 256 + lane * 4, s_xp + 0 * 2 * CHF + CHF + r * 256);
        #pragma unroll
        for (int r = 0; r < 8; ++r) gl16(xb1 + CHF + r * 256 + lane * 4, s_xp + 1 * 2 * CHF + CHF + r * 256);

        for (int q = 0; q < NCHUNK; ++q) {
            if (q == NCHUNK - 1) asm volatile("s_waitcnt vmcnt(0)" ::: "memory");
            else                 asm volatile("s_waitcnt vmcnt(16)" ::: "memory");
            while (ld_acq(&s_cons) < q - 1) {         // gx bufs (q&1) free?
                __builtin_amdgcn_s_sleep(2);
            }

            #pragma unroll
            for (int row = 0; row < 2; ++row) {
                const f2* xc  = (const f2*)(s_xp + row * 2 * CHF + (q & 1) * CHF);
                float*    gxd = s_gx + row * 2 * GXF + (q & 1) * GXF;
                #pragma unroll 2
                for (int s = 0; s < CH; ++s) {
                    const f2* xt2 = xc + s * (INn / 2);
                    f2 a0, a1, a2, a3, c0, c1, c2, c3;
                    a0 = a1 = a2 = a3 = c0 = c1 = c2 = c3 = (f2)(0.f);
                    #pragma unroll
                    for (int i = 0; i < INn / 2; i += 4) {
                        const f2 x0 = xt2[i], x1 = xt2[i + 1], x2 = xt2[i + 2], x3 = xt2[i + 3];
                        a0 += wA[i] * x0;     c0 += wB[i] * x0;
                        a1 += wA[i + 1] * x1; c1 += wB[i + 1] * x1;
                        a2 += wA[i + 2] * x2; c2 += wB[i + 2] * x2;
                        a3 += wA[i + 3] * x3; c3 += wB[i + 3] * x3;
                    }
                    gxd[s * 128 + rA] = biasA + hadd((a0 + a1) + (a2 + a3));
                    gxd[s * 128 + rB] = biasB + hadd((c0 + c1) + (c2 + c3));
                }
            }
            if (lane == 0) st_rel(&s_prog, q + 1);   // release: gx drained first
            if (q + 2 < NCHUNK) {                    // refill freed x buffers
                const float* s0 = xb0 + (size_t)(q + 2) * CHF;
                const float* s1 = xb1 + (size_t)(q + 2) * CHF;
                float* d0 = s_xp + 0 * 2 * CHF + (q & 1) * CHF;
                float* d1 = s_xp + 1 * 2 * CHF + (q & 1) * CHF;
                #pragma unroll
                for (int r = 0; r < 8; ++r) gl16(s0 + r * 256 + lane * 4, d0 + r * 256);
                #pragma unroll
                for (int r = 0; r < 8; ++r) gl16(s1 + r * 256 + lane * 4, d1 + r * 256);
            }
        }
    } else {
        // ========== consumer wave: TWO interleaved serial chains =============
        float whA_[Hn], whB_[Hn];        // volatile-pinned, shared by chains
        {
            const volatile float* pA = W_hh + (size_t)rA * Hn;
            const volatile float* pB = W_hh + (size_t)(rA + 2 * Hn) * Hn;
            #pragma unroll
            for (int i = 0; i < Hn; ++i) { whA_[i] = pA[i]; whB_[i] = pB[i]; }
        }

        // P[cls] = ( dot(W_ih[rA,64:128], emb[cls]), dot(W_ih[rB,64:128], emb[cls]) )
        f2 P[NC];
        #pragma unroll
        for (int cls = 0; cls < NC; ++cls) {
            float pa = 0.f, pb = 0.f;
            for (int i = 0; i < INn; ++i) {
                const float e = emb[cls * INn + i];
                pa += W_ih[(size_t)rA * 2 * INn + INn + i] * e;
                pb += W_ih[(size_t)(rA + 2 * Hn) * 2 * INn + INn + i] * e;
            }
            f2 v; v.x = pa; v.y = pb; P[cls] = v;
        }

        const int cl = lane % 5;         // per-lane classifier class
        float wfc_[Hn];                  // volatile-pinned, shared by chains
        {
            const volatile float* pf = W_fc + (size_t)cl * Hn;
            #pragma unroll
            for (int i = 0; i < Hn; ++i) wfc_[i] = pf[i];
        }
        const float bfL = b_fc[cl];

        const float zsB  = even ? 2.f : 1.f;   // g: tanh(z) = 2*sig(2z)-1
        const float mulB = even ? 2.f : 1.f;
        const float addB = even ? -1.f : 0.f;

        float cs0 = 0.f, cs1 = 0.f;            // cell states
        f2 Ps0, Ps1; Ps0.x = Ps0.y = Ps1.x = Ps1.y = 0.f;
        float h0 = 0.f, h1 = 0.f;

        // activations + cell update (R7 verbatim), per-chain via cst ref
        auto acts = [&](float accA, float accB, float& cst) -> float {
            const float actA = rcpf(1.f + __expf(-accA));
            const float sgB  = rcpf(1.f + __expf(-zsB * accB));
            const float actB = fmaf(sgB, mulB, addB);

            const float qA = dpp_swap1(actA);
            const float qB = dpp_swap1(actB);
            const float iv = even ? actA : qA;
            const float fv = even ? qA : actA;
            const float gv = even ? actB : qB;
            const float ov = even ? qB : actB;

            cst = fmaf(fv, cst, iv * gv);
            const float e2 = __expf(2.f * cst);
            const float th = 1.f - 2.f * rcpf(e2 + 1.f);
            return ov * th;
        };

        // classifier dot for one chain (R7's chain-exact mapping)
        auto clsdot = [&](const float* hs) -> float {
            float zc[8];
            #pragma unroll
            for (int k = 0; k < 8; ++k) zc[k] = 0.f;
            #pragma unroll
            for (int mm = 0; mm < Hn; ++mm) {
                const int k = ((mm >> 1) & 3) * 2 + (mm & 1);
                zc[k] = fmaf(wfc_[mm], hs[mm], zc[k]);
            }
            return ((zc[0] + zc[2]) + (zc[4] + zc[6]))
                 + ((zc[1] + zc[3]) + (zc[5] + zc[7])) + bfL;
        };

        // one interleaved step t>=1 for both chains
        auto step2 = [&](int t, const float* gx0, const float* gx1, int s) {
            const float gA0 = gx0[s * 128 + rA];
            const float gB0 = gx0[s * 128 + rB];
            const float gA1 = gx1[s * 128 + rA];
            const float gB1 = gx1[s * 128 + rB];

            float hs0[Hn], hs1[Hn];
            #pragma unroll
            for (int mm = 0; mm < Hn; ++mm) {
                hs0[mm] = rlane(h0, 2 * mm);
                hs1[mm] = rlane(h1, 2 * mm);
            }

            // matvecs + classifier dots, chains interleaved per mm
            float zA0[8], zB0[8], zA1[8], zB1[8];
            float zc0[8], zc1[8];
            #pragma unroll
            for (int k = 0; k < 8; ++k) {
                zA0[k] = zB0[k] = zA1[k] = zB1[k] = 0.f;
                zc0[k] = zc1[k] = 0.f;
            }
            #pragma unroll
            for (int mm = 0; mm < Hn; ++mm) {
                const int k = ((mm >> 1) & 3) * 2 + (mm & 1);
                zc0[k] = fmaf(wfc_[mm], hs0[mm], zc0[k]);
                zc1[k] = fmaf(wfc_[mm], hs1[mm], zc1[k]);
                zA0[k] = fmaf(whA_[mm], hs0[mm], zA0[k]);
                zA1[k] = fmaf(whA_[mm], hs1[mm], zA1[k]);
                zB0[k] = fmaf(whB_[mm], hs0[mm], zB0[k]);
                zB1[k] = fmaf(whB_[mm], hs1[mm], zB1[k]);
            }
            const float z0 = ((zc0[0] + zc0[2]) + (zc0[4] + zc0[6]))
                           + ((zc0[1] + zc0[3]) + (zc0[5] + zc0[7])) + bfL;
            const float z1 = ((zc1[0] + zc1[2]) + (zc1[4] + zc1[6]))
                           + ((zc1[1] + zc1[3]) + (zc1[5] + zc1[7])) + bfL;

            // argmax + Ps select, chain 0 (first-max-wins, np.argmax order)
            {
                const float p0 = rlane(z0, 0), p1 = rlane(z0, 1), p2 = rlane(z0, 2),
                            p3 = rlane(z0, 3), p4 = rlane(z0, 4);
                float bv = p0; int am = 0;
                bool g1 = p1 > bv; bv = g1 ? p1 : bv; am = g1 ? 1 : am;
                bool g2 = p2 > bv; bv = g2 ? p2 : bv; am = g2 ? 2 : am;
                bool g3 = p3 > bv; bv = g3 ? p3 : bv; am = g3 ? 3 : am;
                bool g4 = p4 > bv; bv = g4 ? p4 : bv; am = g4 ? 4 : am;
                Ps0 = (am == 0) ? P[0] : (am == 1) ? P[1] : (am == 2) ? P[2]
                    : (am == 3) ? P[3] : P[4];
            }
            // chain 1
            {
                const float p0 = rlane(z1, 0), p1 = rlane(z1, 1), p2 = rlane(z1, 2),
                            p3 = rlane(z1, 3), p4 = rlane(z1, 4);
                float bv = p0; int am = 0;
                bool g1 = p1 > bv; bv = g1 ? p1 : bv; am = g1 ? 1 : am;
                bool g2 = p2 > bv; bv = g2 ? p2 : bv; am = g2 ? 2 : am;
                bool g3 = p3 > bv; bv = g3 ? p3 : bv; am = g3 ? 3 : am;
                bool g4 = p4 > bv; bv = g4 ? p4 : bv; am = g4 ? 4 : am;
                Ps1 = (am == 0) ? P[0] : (am == 1) ? P[1] : (am == 2) ? P[2]
                    : (am == 3) ? P[3] : P[4];
            }

            const float hA0 = ((zA0[0] + zA0[2]) + (zA0[4] + zA0[6]))
                            + ((zA0[1] + zA0[3]) + (zA0[5] + zA0[7]));
            const float hB0 = ((zB0[0] + zB0[2]) + (zB0[4] + zB0[6]))
                            + ((zB0[1] + zB0[3]) + (zB0[5] + zB0[7]));
            const float hA1 = ((zA1[0] + zA1[2]) + (zA1[4] + zA1[6]))
                            + ((zA1[1] + zA1[3]) + (zA1[5] + zA1[7]));
            const float hB1 = ((zB1[0] + zB1[2]) + (zB1[4] + zB1[6]))
                            + ((zB1[1] + zB1[3]) + (zB1[5] + zB1[7]));

            const float acc0A = gA0 + hA0 + Ps0.x;
            const float acc0B = gB0 + hB0 + Ps0.y;
            const float acc1A = gA1 + hA1 + Ps1.x;
            const float acc1B = gB1 + hB1 + Ps1.y;

            h0 = acts(acc0A, acc0B, cs0);
            h1 = acts(acc1A, acc1B, cs1);

            // raw logits straight to global (postpass applies log-softmax)
            if (lane < NC) {
                ob0[(size_t)(t - 1) * NC + lane] = z0;
                ob1[(size_t)(t - 1) * NC + lane] = z1;
            }
        };

        // ---- chunk 0: peel t=0 (h=0, prev=0 -> acc = gx + bias directly) ----
        while (ld_acq(&s_prog) < 1) { }
        {
            const float* gx0 = s_gx;                    // row0 buf0
            const float* gx1 = s_gx + 2 * GXF;          // row1 buf0
            h0 = acts(gx0[rA], gx0[rB], cs0);           // t = 0
            h1 = acts(gx1[rA], gx1[rB], cs1);
            for (int s = 1; s < CH; ++s) step2(s, gx0, gx1, s);
            if (lane == 0) st_rel(&s_cons, 1);
        }
        // ---- chunks 1..63 ----
        for (int q = 1; q < NCHUNK; ++q) {
            while (ld_acq(&s_prog) < q + 1) { }
            const float* gx0 = s_gx + (q & 1) * GXF;
            const float* gx1 = s_gx + 2 * GXF + (q & 1) * GXF;
            for (int s = 0; s < CH; ++s) step2(q * CH + s, gx0, gx1, s);
            if (lane == 0) st_rel(&s_cons, q + 1);
        }
        // ---- epilogue: classifier for t = Tn-1, both chains, raw store ----
        {
            float hs0[Hn], hs1[Hn];
            #pragma unroll
            for (int mm = 0; mm < Hn; ++mm) {
                hs0[mm] = rlane(h0, 2 * mm);
                hs1[mm] = rlane(h1, 2 * mm);
            }
            const float z0 = clsdot(hs0);
            const float z1 = clsdot(hs1);
            if (lane < NC) {
                ob0[(size_t)(Tn - 1) * NC + lane] = z0;
                ob1[(size_t)(Tn - 1) * NC + lane] = z1;
            }
        }
    }
}

// in-place log-softmax postpass: out[row][0..4] -= lse(row).
// EXACT max/sum order of the R7 drain (bit-identical results).
__global__ __launch_bounds__(256)
void logsoftmax_pp(float* __restrict__ out)
{
    const int r = blockIdx.x * 256 + threadIdx.x;    // 524288 rows
    float* p = out + (size_t)r * NC;
    const float z0 = p[0], z1 = p[1], z2 = p[2], z3 = p[3], z4 = p[4];
    float bv = z0;
    bv = (z1 > bv) ? z1 : bv;
    bv = (z2 > bv) ? z2 : bv;
    bv = (z3 > bv) ? z3 : bv;
    bv = (z4 > bv) ? z4 : bv;
    const float se = __expf(z0 - bv) + __expf(z1 - bv) + __expf(z2 - bv)
                   + __expf(z3 - bv) + __expf(z4 - bv);
    const float lse = bv + __logf(se);
    p[0] = z0 - lse;
    p[1] = z1 - lse;
    p[2] = z2 - lse;
    p[3] = z3 - lse;
    p[4] = z4 - lse;
}

} // namespace

extern "C" void kernel_launch(void* const* d_in, const int* in_sizes, int n_in,
                              void* d_out, int out_size, void* d_ws, size_t ws_size,
                              hipStream_t stream) {
    (void)in_sizes; (void)n_in; (void)d_ws; (void)ws_size; (void)out_size;
    const float* x    = (const float*)d_in[0];
    // d_in[1] x_lengths (all == T), d_in[2] edge_list: unused
    const float* W_ih = (const float*)d_in[3];
    const float* W_hh = (const float*)d_in[4];
    const float* b_ih = (const float*)d_in[5];
    const float* b_hh = (const float*)d_in[6];
    const float* W_fc = (const float*)d_in[7];
    const float* b_fc = (const float*)d_in[8];
    const float* emb  = (const float*)d_in[9];
    float* out = (float*)d_out;

    hipLaunchKernelGGL(ar_decode2, dim3(128), dim3(128), 0, stream,
                       x, W_ih, W_hh, b_ih, b_hh, W_fc, b_fc, emb, out);
    hipLaunchKernelGGL(logsoftmax_pp, dim3(2048), dim3(256), 0, stream, out);
}

// Round 6
// 918.517 us; speedup vs baseline: 2.2836x; 2.2836x over previous
//
#include <hip/hip_runtime.h>

// AR LSTM decoder, B=256, T=2048, IN=64, H=32, NCLS=5.
//
// R9 (resubmit after infra failure): minimum-instruction single chain.
// Empirical law from R4-R8: per-wave time ~ 6 cy/instruction regardless of
// structure (2-chain R8 scaled 1.87x -> issue-bound, not stall-bound).
// So: cut instructions.
//   - R6's packed h-broadcast: 1 ds_write + 8 ds_read_b128 + pk_fma matvec
//     (48 packed) + packed classifier (16) — R6-proven bit-exact codegen.
//   - all-lane h write (pairs write identical value; no exec juggling).
//   - packed gx: producer stores (gA,gB) as f2 -> 1 ds_read_b64/step.
//   - streamlined argmax: track bv/Ps via cndmask chain (no am), same
//     first-max-wins compare sequence -> bit-identical.
//   - raw logits to out[] + separate log-softmax postpass (R8-proven,
//     bit-identical ordering).
// Producer gx pipeline otherwise verbatim from the proven kernel.

namespace {

typedef float f2 __attribute__((ext_vector_type(2)));
typedef unsigned int u32;
typedef const __attribute__((address_space(1))) u32* gas_ptr;
typedef __attribute__((address_space(3))) u32* las_ptr;

constexpr int Tn  = 2048;
constexpr int INn = 64;
constexpr int Hn  = 32;
constexpr int NC  = 5;
constexpr int CH  = 32;            // steps per chunk
constexpr int CHF = CH * INn;      // 2048 floats x-chunk (8 KB)
constexpr int GXF = CH * 128;      // 4096 floats gx-chunk (16 KB)
constexpr int NCHUNK = Tn / CH;    // 64

__device__ __forceinline__ float rcpf(float x) { return __builtin_amdgcn_rcpf(x); }
__device__ __forceinline__ float hadd(f2 v) { return v.x + v.y; }

__device__ __forceinline__ float rlane(float x, int l) {
    return __int_as_float(__builtin_amdgcn_readlane(__float_as_int(x), l));
}

__device__ __forceinline__ float dpp_swap1(float x) {   // quad_perm xor 1
    int t = __builtin_amdgcn_update_dpp(0, __float_as_int(x), 0xB1, 0xF, 0xF, true);
    return __int_as_float(t);
}

__device__ __forceinline__ void gl16(const float* g, float* l) {
    __builtin_amdgcn_global_load_lds((gas_ptr)g, (las_ptr)l, 16, 0, 0);
}

__device__ __forceinline__ int ld_acq(int* p) {
    return __hip_atomic_load(p, __ATOMIC_ACQUIRE, __HIP_MEMORY_SCOPE_WORKGROUP);
}
__device__ __forceinline__ void st_rel(int* p, int v) {
    __hip_atomic_store(p, v, __ATOMIC_RELEASE, __HIP_MEMORY_SCOPE_WORKGROUP);
}

__global__ __launch_bounds__(128, 1)
void ar_decode(const float* __restrict__ x,
               const float* __restrict__ W_ih,
               const float* __restrict__ W_hh,
               const float* __restrict__ b_ih,
               const float* __restrict__ b_hh,
               const float* __restrict__ W_fc,
               const float* __restrict__ b_fc,
               const float* __restrict__ emb,
               float* __restrict__ out)
{
    const int b    = blockIdx.x;
    const int tid  = threadIdx.x;
    const int lane = tid & 63;
    const int m    = lane >> 1;
    const int par  = lane & 1;
    const bool even = (par == 0);
    const int rA = par * Hn + m;            // i-row (par0) or f-row (par1)
    const int rB = rA + 2 * Hn;             // g-row (par0) or o-row (par1)

    __shared__ __align__(16) float s_xp[2 * CHF];   // 16 KB x staging
    __shared__ __align__(16) float s_gx[2 * GXF];   // 32 KB gx double buffer (packed f2)
    __shared__ __align__(16) float s_h[Hn];         // h(t) broadcast
    __shared__ int s_prog;   // chunks produced
    __shared__ int s_cons;   // chunks consumed

    if (tid == 0) { s_prog = 0; s_cons = 0; }
    __syncthreads();

    const float* __restrict__ xb = x + (size_t)b * Tn * INn;
    float* __restrict__ ob = out + (size_t)b * Tn * NC;

    if (tid >= 64) {
        // ===================== producer wave (proven; packed gx write) =======
        f2 wA[INn / 2], wB[INn / 2];     // 128 VGPR — volatile-pinned loads
        {
            const volatile f2* pA = (const volatile f2*)(W_ih + (size_t)rA * 2 * INn);
            const volatile f2* pB = (const volatile f2*)(W_ih + (size_t)rB * 2 * INn);
            #pragma unroll
            for (int i = 0; i < INn / 2; ++i) { wA[i] = pA[i]; wB[i] = pB[i]; }
        }
        const float biasA = b_ih[rA] + b_hh[rA];
        const float biasB = b_ih[rB] + b_hh[rB];

        #pragma unroll
        for (int r = 0; r < 8; ++r) gl16(xb + r * 256 + lane * 4, s_xp + r * 256);
        #pragma unroll
        for (int r = 0; r < 8; ++r) gl16(xb + CHF + r * 256 + lane * 4, s_xp + CHF + r * 256);

        for (int q = 0; q < NCHUNK; ++q) {
            if (q == NCHUNK - 1) asm volatile("s_waitcnt vmcnt(0)" ::: "memory");
            else                 asm volatile("s_waitcnt vmcnt(8)" ::: "memory");
            while (ld_acq(&s_cons) < q - 1) { }   // gx buf (q&1) free?

            const f2* xc  = (const f2*)(s_xp + (q & 1) * CHF);
            f2*       gxd = (f2*)(s_gx + (q & 1) * GXF);
            #pragma unroll 2
            for (int s = 0; s < CH; ++s) {
                const f2* xt2 = xc + s * (INn / 2);
                f2 a0, a1, a2, a3, c0, c1, c2, c3;
                a0 = a1 = a2 = a3 = c0 = c1 = c2 = c3 = (f2)(0.f);
                #pragma unroll
                for (int i = 0; i < INn / 2; i += 4) {
                    const f2 x0 = xt2[i], x1 = xt2[i + 1], x2 = xt2[i + 2], x3 = xt2[i + 3];
                    a0 += wA[i] * x0;     c0 += wB[i] * x0;
                    a1 += wA[i + 1] * x1; c1 += wB[i + 1] * x1;
                    a2 += wA[i + 2] * x2; c2 += wB[i + 2] * x2;
                    a3 += wA[i + 3] * x3; c3 += wB[i + 3] * x3;
                }
                f2 g;
                g.x = biasA + hadd((a0 + a1) + (a2 + a3));
                g.y = biasB + hadd((c0 + c1) + (c2 + c3));
                gxd[s * 64 + rA] = g;                 // 1 ds_write_b64, packed
            }
            if (lane == 0) st_rel(&s_prog, q + 1);   // release: gx drained first
            if (q + 2 < NCHUNK) {                    // refill the freed x buffer
                const float* src = xb + (size_t)(q + 2) * CHF;
                float* dst = s_xp + (q & 1) * CHF;
                #pragma unroll
                for (int r = 0; r < 8; ++r) gl16(src + r * 256 + lane * 4, dst + r * 256);
            }
        }
    } else {
        // ===================== consumer wave (serial chain) ==================
        f2 whA[Hn / 2], whB[Hn / 2];     // 64 VGPR — volatile-pinned loads
        {
            const volatile f2* pA = (const volatile f2*)(W_hh + (size_t)rA * Hn);
            const volatile f2* pB = (const volatile f2*)(W_hh + (size_t)rB * Hn);
            #pragma unroll
            for (int i = 0; i < Hn / 2; ++i) { whA[i] = pA[i]; whB[i] = pB[i]; }
        }

        // P[cls] = ( dot(W_ih[rA,64:128], emb[cls]), dot(W_ih[rB,64:128], emb[cls]) )
        f2 P[NC];
        #pragma unroll
        for (int cls = 0; cls < NC; ++cls) {
            float pa = 0.f, pb = 0.f;
            for (int i = 0; i < INn; ++i) {
                const float e = emb[cls * INn + i];
                pa += W_ih[(size_t)rA * 2 * INn + INn + i] * e;
                pb += W_ih[(size_t)rB * 2 * INn + INn + i] * e;
            }
            f2 v; v.x = pa; v.y = pb; P[cls] = v;
        }

        // per-lane classifier row: class cl = lane % 5 (lanes 0..4 are read)
        const int cl = lane % 5;
        f2 wfcL[Hn / 2];                 // 32 VGPR — volatile-pinned
        {
            const volatile f2* pf = (const volatile f2*)(W_fc + (size_t)cl * Hn);
            #pragma unroll
            for (int i = 0; i < Hn / 2; ++i) wfcL[i] = pf[i];
        }
        const float bfL = b_fc[cl];

        const float zsB  = even ? 2.f : 1.f;   // g: tanh(z) = 2*sig(2z)-1
        const float mulB = even ? 2.f : 1.f;
        const float addB = even ? -1.f : 0.f;

        float cst = 0.f;

        // activations + cell update + all-lane h write (identical math)
        auto acts = [&](float accA, float accB) {
            const float actA = rcpf(1.f + __expf(-accA));
            const float sgB  = rcpf(1.f + __expf(-zsB * accB));
            const float actB = fmaf(sgB, mulB, addB);

            const float qA = dpp_swap1(actA);
            const float qB = dpp_swap1(actB);
            const float iv = even ? actA : qA;
            const float fv = even ? qA : actA;
            const float gv = even ? actB : qB;
            const float ov = even ? qB : actB;

            cst = fmaf(fv, cst, iv * gv);
            const float e2 = __expf(2.f * cst);
            const float th = 1.f - 2.f * rcpf(e2 + 1.f);
            const float h  = ov * th;
            s_h[m] = h;                 // both parities write identical value
        };

        // one step t >= 1: classify h(t-1), matvec, update, raw-store t-1
        auto full_step = [&](int t, const float* gxc, int s) {
            const f2* hp = (const f2*)s_h;   // h(t-1), written by prev step
            f2 hv[Hn / 2];
            #pragma unroll
            for (int i = 0; i < Hn / 2; ++i) hv[i] = hp[i];

            const f2 g = ((const f2*)gxc)[s * 64 + rA];   // (gA, gB) packed

            // ---- classifier for step t-1 (packed, R6-verbatim ordering) ----
            f2 z0, z1, z2, z3;
            z0 = z1 = z2 = z3 = (f2)(0.f);
            #pragma unroll
            for (int i = 0; i < Hn / 2; i += 4) {
                z0 += wfcL[i] * hv[i];         z1 += wfcL[i + 1] * hv[i + 1];
                z2 += wfcL[i + 2] * hv[i + 2]; z3 += wfcL[i + 3] * hv[i + 3];
            }
            const float z = hadd((z0 + z1) + (z2 + z3)) + bfL;
            const float p0 = rlane(z, 0), p1 = rlane(z, 1), p2 = rlane(z, 2),
                        p3 = rlane(z, 3), p4 = rlane(z, 4);

            // argmax -> Ps directly (first-max-wins, same compare sequence)
            float bv = p0; f2 Ps = P[0];
            const bool g1 = p1 > bv; bv = g1 ? p1 : bv; Ps = g1 ? P[1] : Ps;
            const bool g2 = p2 > bv; bv = g2 ? p2 : bv; Ps = g2 ? P[2] : Ps;
            const bool g3 = p3 > bv; bv = g3 ? p3 : bv; Ps = g3 ? P[3] : Ps;
            const bool g4 = p4 > bv; bv = g4 ? p4 : bv; Ps = g4 ? P[4] : Ps;

            // ---- W_hh · h(t-1) (R6-verbatim packed chains) ----
            f2 aA0, aA1, aA2, aA3, aB0, aB1, aB2, aB3;
            aA0 = aA1 = aA2 = aA3 = aB0 = aB1 = aB2 = aB3 = (f2)(0.f);
            #pragma unroll
            for (int i = 0; i < Hn / 2; i += 4) {
                const f2 h0 = hv[i], h1 = hv[i + 1], h3 = hv[i + 2], h4 = hv[i + 3];
                aA0 += whA[i] * h0;     aB0 += whB[i] * h0;
                aA1 += whA[i + 1] * h1; aB1 += whB[i + 1] * h1;
                aA2 += whA[i + 2] * h3; aB2 += whB[i + 2] * h3;
                aA3 += whA[i + 3] * h4; aB3 += whB[i + 3] * h4;
            }
            const float accA = g.x + hadd((aA0 + aA1) + (aA2 + aA3)) + Ps.x;
            const float accB = g.y + hadd((aB0 + aB1) + (aB2 + aB3)) + Ps.y;

            acts(accA, accB);           // ends with s_h write of h(t)

            // ---- raw logit store for t-1 (postpass applies log-softmax) ----
            if (lane < NC) {
                float pv = p0;
                pv = (lane == 1) ? p1 : pv;
                pv = (lane == 2) ? p2 : pv;
                pv = (lane == 3) ? p3 : pv;
                pv = (lane == 4) ? p4 : pv;
                ob[(size_t)(t - 1) * NC + lane] = pv;
            }
        };

        // ---- chunk 0: peel t=0 (h=0, prev=0 -> acc = gx + bias directly) ----
        while (ld_acq(&s_prog) < 1) { }
        {
            const float* gxc = s_gx;
            const f2 g0 = ((const f2*)gxc)[rA];
            acts(g0.x, g0.y);                       // t = 0
            #pragma unroll 4
            for (int s = 1; s < CH; ++s) full_step(s, gxc, s);
            if (lane == 0) st_rel(&s_cons, 1);
        }
        // ---- chunks 1..63 ----
        for (int q = 1; q < NCHUNK; ++q) {
            while (ld_acq(&s_prog) < q + 1) { }
            const float* gxc = s_gx + (q & 1) * GXF;
            #pragma unroll 4
            for (int s = 0; s < CH; ++s) full_step(q * CH + s, gxc, s);
            if (lane == 0) st_rel(&s_cons, q + 1);
        }
        // ---- epilogue: classifier for t = Tn-1, raw store ----
        {
            const f2* hp = (const f2*)s_h;
            f2 hv[Hn / 2];
            #pragma unroll
            for (int i = 0; i < Hn / 2; ++i) hv[i] = hp[i];
            f2 z0, z1, z2, z3;
            z0 = z1 = z2 = z3 = (f2)(0.f);
            #pragma unroll
            for (int i = 0; i < Hn / 2; i += 4) {
                z0 += wfcL[i] * hv[i];         z1 += wfcL[i + 1] * hv[i + 1];
                z2 += wfcL[i + 2] * hv[i + 2]; z3 += wfcL[i + 3] * hv[i + 3];
            }
            const float z = hadd((z0 + z1) + (z2 + z3)) + bfL;
            const float p0 = rlane(z, 0), p1 = rlane(z, 1), p2 = rlane(z, 2),
                        p3 = rlane(z, 3), p4 = rlane(z, 4);
            if (lane < NC) {
                float pv = p0;
                pv = (lane == 1) ? p1 : pv;
                pv = (lane == 2) ? p2 : pv;
                pv = (lane == 3) ? p3 : pv;
                pv = (lane == 4) ? p4 : pv;
                ob[(size_t)(Tn - 1) * NC + lane] = pv;
            }
        }
    }
}

// in-place log-softmax postpass: out[row][0..4] -= lse(row).
// EXACT max/sum order of the previous kernels (bit-identical results).
__global__ __launch_bounds__(256)
void logsoftmax_pp(float* __restrict__ out)
{
    const int r = blockIdx.x * 256 + threadIdx.x;    // 524288 rows
    float* p = out + (size_t)r * NC;
    const float z0 = p[0], z1 = p[1], z2 = p[2], z3 = p[3], z4 = p[4];
    float bv = z0;
    bv = (z1 > bv) ? z1 : bv;
    bv = (z2 > bv) ? z2 : bv;
    bv = (z3 > bv) ? z3 : bv;
    bv = (z4 > bv) ? z4 : bv;
    const float se = __expf(z0 - bv) + __expf(z1 - bv) + __expf(z2 - bv)
                   + __expf(z3 - bv) + __expf(z4 - bv);
    const float lse = bv + __logf(se);
    p[0] = z0 - lse;
    p[1] = z1 - lse;
    p[2] = z2 - lse;
    p[3] = z3 - lse;
    p[4] = z4 - lse;
}

} // namespace

extern "C" void kernel_launch(void* const* d_in, const int* in_sizes, int n_in,
                              void* d_out, int out_size, void* d_ws, size_t ws_size,
                              hipStream_t stream) {
    (void)in_sizes; (void)n_in; (void)d_ws; (void)ws_size; (void)out_size;
    const float* x    = (const float*)d_in[0];
    // d_in[1] x_lengths (all == T), d_in[2] edge_list: unused
    const float* W_ih = (const float*)d_in[3];
    const float* W_hh = (const float*)d_in[4];
    const float* b_ih = (const float*)d_in[5];
    const float* b_hh = (const float*)d_in[6];
    const float* W_fc = (const float*)d_in[7];
    const float* b_fc = (const float*)d_in[8];
    const float* emb  = (const float*)d_in[9];
    float* out = (float*)d_out;

    hipLaunchKernelGGL(ar_decode, dim3(256), dim3(128), 0, stream,
                       x, W_ih, W_hh, b_ih, b_hh, W_fc, b_fc, emb, out);
    hipLaunchKernelGGL(logsoftmax_pp, dim3(2048), dim3(256), 0, stream, out);
}